// Round 1
// 470.530 us; speedup vs baseline: 1.0271x; 1.0271x over previous
//
#include <hip/hip_runtime.h>
#include <math.h>

// alpha-entmax via bisection (ref: entmax.EntmaxBisect, 50 iters).
// Single fused streaming pass.
//
// Facts exploited:
//  * Every bisection iterate tau >= gmax-1, so elements with X <= gmax-1
//    contribute 0 to all sums and output exactly 0 (~98% of row here).
//  * Candidate filter only needs a threshold <= gmax-1: ANY running-max
//    lower bound works; extra candidates contribute 0 to the solve and
//    scatter p=0 onto already-zeroed output -> harmless. Hence no
//    ordering requirement on the LDS running max at all.
//  * alpha=1.5: f(tau)=sum max(X-tau,0)^2-1 convex decreasing; Newton from
//    tau_lo converges monotonically, ~8-12 iters to fp32 eps (early exit).
//
// R5 (this round): rocprof showed VGPR_Count=32 -> the R4 "pipelined"
// loads were re-serialized by the register-pressure-minimizing scheduler
// (MLP ~1/wave, 2.5 TB/s plateau). Restructure:
//  * flat 16-deep per-thread prefetch (all loads, then all zero-stores),
//    pinned with sched_barrier(0); __launch_bounds__(512,2) so ~96 live
//    VGPRs neither spill nor get sunk.
//  * ONE LDS max round-trip per row (wave-reduce max, 1 atomicMax/wave,
//    relaxed read-back) instead of per-group volatile chains.
//  * wave-aggregated candidate append: shfl exclusive scan + 1
//    atomicAdd/wave (was ~128 same-address LDS atomics per group).
//  * candidate compare in raw-x domain (threshold scaled once by 1/am1,
//    valid since am1>0 makes x -> x*am1 monotone).

#define D_DIM   32000
#define NV4     (D_DIM / 4)          // 8000 float4 per row
#define BLOCK   512
#define NWAVE   (BLOCK / 64)         // 8
#define NCHUNK  16                   // float4 chunks per thread (ceil 8000/512)
#define CAP     6144                 // candidate capacity (val+u16 idx = 36 KB)
#define NEWTON_MAX 30
#define NITER   50

__device__ __forceinline__ float wave_sum(float v) {
#pragma unroll
    for (int off = 32; off > 0; off >>= 1) v += __shfl_xor(v, off, 64);
    return v;
}
__device__ __forceinline__ float wave_max(float v) {
#pragma unroll
    for (int off = 32; off > 0; off >>= 1) v = fmaxf(v, __shfl_xor(v, off, 64));
    return v;
}
__device__ __forceinline__ float pf(float z, bool sq, float expo) {
    z = fmaxf(z, 0.0f);
    return sq ? z * z : powf(z, expo);
}
// order-preserving float<->uint maps (for LDS atomicMax running max)
__device__ __forceinline__ unsigned fflip(float f) {
    unsigned u = __float_as_uint(f);
    return u ^ ((u >> 31) ? 0xFFFFFFFFu : 0x80000000u);
}
__device__ __forceinline__ float funflip(unsigned u) {
    return __uint_as_float(u ^ ((u & 0x80000000u) ? 0x80000000u : 0xFFFFFFFFu));
}

__global__ __launch_bounds__(BLOCK, 2)   // VGPR cap 256: room for v[16] + overhead
void entmax_bisect_kernel(const float* __restrict__ x,
                          const float* __restrict__ alpha_p,
                          float* __restrict__ out) {
    const int row  = blockIdx.x;
    const int tid  = threadIdx.x;
    const int lane = tid & 63;
    const int wid  = tid >> 6;

    __shared__ float          s_val[CAP];    // 24 KB, X-domain values
    __shared__ unsigned short s_idx[CAP];    // 12 KB
    __shared__ float          s_red[NWAVE];
    __shared__ float          s_bc[2];       // tau_final, sum_p
    __shared__ int            s_cnt;
    __shared__ unsigned       s_gmax;        // running max, fflip(X) domain

    const float alpha   = alpha_p[0];
    const float am1     = alpha - 1.0f;
    const float inv_am1 = 1.0f / am1;
    const float expo    = inv_am1;
    const bool  sq      = (expo == 2.0f);    // alpha == 1.5 exact fast path

    const float4* __restrict__ x4 = (const float4*)(x + (size_t)row * D_DIM);
    float4*       __restrict__ o4 = (float4*)(out + (size_t)row * D_DIM);

    if (tid == 0) { s_cnt = 0; s_gmax = 0u; }   // 0u < fflip(any float)
    __syncthreads();

    // ---- Phase 1: issue ALL 16 loads, then ALL 16 zero-stores ----
    // sched_barrier(0) pins the issue order: 16 loads in flight per wave
    // (16 KB/wave MLP) before any dependent compute.
    const float4 zero4 = make_float4(0.f, 0.f, 0.f, 0.f);
    float4 v[NCHUNK];
#pragma unroll
    for (int k = 0; k < NCHUNK; ++k) {
        const int i4 = tid + (k << 9);           // tid + k*BLOCK
        if (i4 < NV4) v[k] = x4[i4];
        else          v[k] = make_float4(-INFINITY, -INFINITY, -INFINITY, -INFINITY);
    }
    __builtin_amdgcn_sched_barrier(0);
#pragma unroll
    for (int k = 0; k < NCHUNK; ++k) {
        const int i4 = tid + (k << 9);
        if (i4 < NV4) o4[i4] = zero4;
    }
    __builtin_amdgcn_sched_barrier(0);

    // ---- Phase 2: row max — one LDS round trip per wave ----
    float tm = -INFINITY;
#pragma unroll
    for (int k = 0; k < NCHUNK; ++k)
        tm = fmaxf(tm, fmaxf(fmaxf(v[k].x, v[k].y), fmaxf(v[k].z, v[k].w)));
    const float wm  = wave_max(tm);              // raw-x wave max
    const float wmX = wm * am1;                  // X-domain
    if (lane == 0) atomicMax(&s_gmax, fflip(wmX));
    const unsigned r = __hip_atomic_load(&s_gmax, __ATOMIC_RELAXED,
                                         __HIP_MEMORY_SCOPE_WORKGROUP);
    // run <= true gmax always; staleness only adds harmless candidates.
    const float run   = fmaxf(funflip(r), wmX);
    const float thr_x = (run - 1.0f) * inv_am1;  // threshold in raw-x domain

    // ---- Phase 3: candidate append, wave-aggregated ----
    int cnt = 0;
#pragma unroll
    for (int k = 0; k < NCHUNK; ++k) {
        cnt += (v[k].x > thr_x) + (v[k].y > thr_x)
             + (v[k].z > thr_x) + (v[k].w > thr_x);
    }
    // inclusive shfl scan over 64 lanes
    int inc = cnt;
#pragma unroll
    for (int off = 1; off < 64; off <<= 1) {
        const int t = __shfl_up(inc, off, 64);
        if (lane >= off) inc += t;
    }
    const int total = __shfl(inc, 63, 64);
    if (total > 0) {
        int base = 0;
        if (lane == 63) base = atomicAdd(&s_cnt, total);
        base = __shfl(base, 63, 64);
        int pos = base + (inc - cnt);            // exclusive offset
        auto append1 = [&](float val, int idx) {
            if (val > thr_x) {
                if (pos < CAP) {
                    s_val[pos] = val * am1;
                    s_idx[pos] = (unsigned short)idx;
                }
                ++pos;
            }
        };
#pragma unroll
        for (int k = 0; k < NCHUNK; ++k) {
            const int e = (tid << 2) + k * 2048; // element index of v[k].x
            append1(v[k].x, e);     append1(v[k].y, e + 1);
            append1(v[k].z, e + 2); append1(v[k].w, e + 3);
        }
    }
    __syncthreads();
    const int   n_act   = s_cnt;
    const float max_val = funflip(s_gmax);       // exact global max (X-domain)
    const float tau_lo0 = max_val - 1.0f;

    if (n_act <= CAP) {
        // ---- Solve on wave 0 (extras in candidate list contribute exactly 0)
        if (wid == 0) {
            float tau, S;
            if (sq) {
                tau = tau_lo0;                   // monotone Newton
                for (int it = 0; it < NEWTON_MAX; ++it) {
                    float s1 = 0.f, s2 = 0.f;
                    for (int i = lane; i < n_act; i += 64) {
                        const float z = fmaxf(s_val[i] - tau, 0.f);
                        s1 += z; s2 += z * z;
                    }
#pragma unroll
                    for (int off = 32; off > 0; off >>= 1) {
                        s1 += __shfl_xor(s1, off, 64);
                        s2 += __shfl_xor(s2, off, 64);
                    }
                    const float dtau = (s2 - 1.0f) / fmaxf(2.0f * s1, 1e-30f);
                    tau += dtau;
                    if (dtau < 1e-7f * fmaxf(1.0f, fabsf(tau))) break;
                }
                float s2 = 0.f;
                for (int i = lane; i < n_act; i += 64) {
                    const float z = fmaxf(s_val[i] - tau, 0.f);
                    s2 += z * z;
                }
                S = wave_sum(s2);
            } else {
                // generic alpha: faithful 50-step bisection over candidates
                const float tau_hi = max_val - powf(1.0f / (float)D_DIM, am1);
                float dm = tau_hi - tau_lo0;
                float s = 0.f;
                for (int i = lane; i < n_act; i += 64)
                    s += pf(s_val[i] - tau_lo0, sq, expo);
                s = wave_sum(s);
                const float f_lo = s - 1.0f;
                float tlo = tau_lo0, tau_m = tau_lo0, fsum = s;
                for (int it = 0; it < NITER; ++it) {
                    dm *= 0.5f;
                    tau_m = tlo + dm;
                    float t = 0.f;
                    for (int i = lane; i < n_act; i += 64)
                        t += pf(s_val[i] - tau_m, sq, expo);
                    t = wave_sum(t);
                    fsum = t;
                    if ((t - 1.0f) * f_lo >= 0.0f) tlo = tau_m;
                }
                tau = tau_m; S = fsum;
            }
            if (lane == 0) { s_bc[0] = tau; s_bc[1] = S; }
        }
        __syncthreads();   // drains zero stores (vmcnt(0)) + publishes tau

        // ---- Scatter nonzero outputs
        const float tau_f = s_bc[0];
        const float invS  = 1.0f / s_bc[1];
        for (int i = tid; i < n_act; i += BLOCK) {
            const float z = fmaxf(s_val[i] - tau_f, 0.f);
            const float p = sq ? z * z : powf(z, expo);
            out[(size_t)row * D_DIM + s_idx[i]] = p * invS;
        }
    } else {
        // ---- Overflow fallback (pathological inputs only): full-row
        //      50-step bisection re-reading x from global each iteration.
        const float tau_hi = max_val - powf(1.0f / (float)D_DIM, am1);
        float dm = tau_hi - tau_lo0;
        float s = 0.f;
        for (int i4 = tid; i4 < NV4; i4 += BLOCK) {
            float4 vv = x4[i4];
            s += pf(vv.x * am1 - tau_lo0, sq, expo) + pf(vv.y * am1 - tau_lo0, sq, expo)
               + pf(vv.z * am1 - tau_lo0, sq, expo) + pf(vv.w * am1 - tau_lo0, sq, expo);
        }
        s = wave_sum(s);
        __syncthreads();
        if (lane == 0) s_red[wid] = s;
        __syncthreads();
        float tot = 0.f;
#pragma unroll
        for (int w = 0; w < NWAVE; ++w) tot += s_red[w];
        const float f_lo = tot - 1.0f;
        float tlo = tau_lo0, tau_m = tau_lo0, fsum = tot;
        for (int it = 0; it < NITER; ++it) {
            dm *= 0.5f;
            tau_m = tlo + dm;
            float t = 0.f;
            for (int i4 = tid; i4 < NV4; i4 += BLOCK) {
                float4 vv = x4[i4];
                t += pf(vv.x * am1 - tau_m, sq, expo) + pf(vv.y * am1 - tau_m, sq, expo)
                   + pf(vv.z * am1 - tau_m, sq, expo) + pf(vv.w * am1 - tau_m, sq, expo);
            }
            t = wave_sum(t);
            __syncthreads();
            if (lane == 0) s_red[wid] = t;
            __syncthreads();
            float tt = 0.f;
#pragma unroll
            for (int w = 0; w < NWAVE; ++w) tt += s_red[w];
            fsum = tt;
            if ((tt - 1.0f) * f_lo >= 0.0f) tlo = tau_m;
        }
        const float invS = 1.0f / fsum;
        __syncthreads();   // drain zero-fill stores before overwrite
        for (int i4 = tid; i4 < NV4; i4 += BLOCK) {
            float4 vv = x4[i4];
            float4 o;
            o.x = pf(vv.x * am1 - tau_m, sq, expo) * invS;
            o.y = pf(vv.y * am1 - tau_m, sq, expo) * invS;
            o.z = pf(vv.z * am1 - tau_m, sq, expo) * invS;
            o.w = pf(vv.w * am1 - tau_m, sq, expo) * invS;
            o4[i4] = o;
        }
    }
}

extern "C" void kernel_launch(void* const* d_in, const int* in_sizes, int n_in,
                              void* d_out, int out_size, void* d_ws, size_t ws_size,
                              hipStream_t stream) {
    const float* x       = (const float*)d_in[0];
    const float* alpha_p = (const float*)d_in[1];
    float* out           = (float*)d_out;
    const int rows       = in_sizes[0] / D_DIM;   // 2048
    entmax_bisect_kernel<<<rows, BLOCK, 0, stream>>>(x, alpha_p, out);
}

// Round 2
// 449.184 us; speedup vs baseline: 1.0759x; 1.0475x over previous
//
#include <hip/hip_runtime.h>
#include <math.h>

// alpha-entmax via bisection (ref: entmax.EntmaxBisect, 50 iters).
// Single load pass -> register-resident row -> solve -> single write pass.
//
// Facts exploited:
//  * Every bisection iterate tau >= gmax-1, so elements with X <= gmax-1
//    contribute 0 to all sums and output exactly 0 (~98% of row here).
//  * Candidate filter only needs a threshold <= gmax-1: ANY running-max
//    lower bound works; extra candidates contribute exactly 0 to the solve
//    and the final write computes p=0 for them anyway -> harmless.
//  * alpha=1.5: f(tau)=sum max(X-tau,0)^2-1 convex decreasing; Newton from
//    tau_lo converges monotonically, ~8-12 iters to fp32 eps (early exit).
//
// R6: R5's VGPR_Count=44 proved the compiler rematerialized the "16-deep
// prefetch" (re-loads at use sites; legal under __restrict, invisible to
// sched_barrier which only pins the scheduler, not RA). Fixes:
//  * loads issued via asm volatile global_load_dwordx4 ("=v" outputs are
//    not rematerializable/splittable) -> 16 loads truly in flight, 64 data
//    VGPRs truly live; one s_waitcnt vmcnt(0) + sched_barrier(0) (rule:
//    compiler hoists register-only ops past inline-asm waitcnts otherwise).
//  * row lives in registers for the whole kernel -> output written ONCE,
//    coalesced float4, at the end (p=0 computed naturally for inactive
//    elements). Deletes zero-fill double-write (~46 MB), scatter RMW,
//    s_idx (LDS 37.4 -> 24.6 KB), and all store-ordering barriers.

#define D_DIM   32000
#define NV4     (D_DIM / 4)          // 8000 float4 per row
#define BLOCK   512
#define NWAVE   (BLOCK / 64)         // 8
#define NCHUNK  16                   // float4 chunks per thread (ceil 8000/512)
#define CAP     6144                 // candidate capacity (val only = 24 KB)
#define NEWTON_MAX 30
#define NITER   50

typedef float f32x4 __attribute__((ext_vector_type(4)));

__device__ __forceinline__ float wave_sum(float v) {
#pragma unroll
    for (int off = 32; off > 0; off >>= 1) v += __shfl_xor(v, off, 64);
    return v;
}
__device__ __forceinline__ float wave_max(float v) {
#pragma unroll
    for (int off = 32; off > 0; off >>= 1) v = fmaxf(v, __shfl_xor(v, off, 64));
    return v;
}
__device__ __forceinline__ float pf(float z, bool sq, float expo) {
    z = fmaxf(z, 0.0f);
    return sq ? z * z : powf(z, expo);
}
// order-preserving float<->uint maps (for LDS atomicMax running max)
__device__ __forceinline__ unsigned fflip(float f) {
    unsigned u = __float_as_uint(f);
    return u ^ ((u >> 31) ? 0xFFFFFFFFu : 0x80000000u);
}
__device__ __forceinline__ float funflip(unsigned u) {
    return __uint_as_float(u ^ ((u & 0x80000000u) ? 0x80000000u : 0xFFFFFFFFu));
}

__global__ __launch_bounds__(BLOCK, 2)   // VGPR cap 256: v[16] stays in regs
void entmax_bisect_kernel(const float* __restrict__ x,
                          const float* __restrict__ alpha_p,
                          float* __restrict__ out) {
    const int row  = blockIdx.x;
    const int tid  = threadIdx.x;
    const int lane = tid & 63;
    const int wid  = tid >> 6;

    __shared__ float    s_val[CAP];    // 24 KB, X-domain candidate values
    __shared__ float    s_red[NWAVE];
    __shared__ float    s_bc[2];       // tau_final, sum_p
    __shared__ int      s_cnt;
    __shared__ unsigned s_gmax;        // running max, fflip(X) domain

    const float alpha   = alpha_p[0];
    const float am1     = alpha - 1.0f;
    const float inv_am1 = 1.0f / am1;
    const float expo    = inv_am1;
    const bool  sq      = (expo == 2.0f);    // alpha == 1.5 exact fast path

    const float* __restrict__ rowp = x + (size_t)row * D_DIM;
    const float4* __restrict__ x4  = (const float4*)rowp;
    float4*       __restrict__ o4  = (float4*)(out + (size_t)row * D_DIM);

    if (tid == 0) { s_cnt = 0; s_gmax = 0u; }   // 0u < fflip(any float)
    __syncthreads();

    // ---- Phase 1: 16 loads via inline asm — forced MLP, forced liveness ----
    f32x4 v[NCHUNK];
#pragma unroll
    for (int k = 0; k < NCHUNK; ++k) {
        const int i4   = tid + (k << 9);               // tid + k*BLOCK
        const int safe = (i4 < NV4) ? i4 : (NV4 - 1);  // clamp: valid addr, masked below
        const unsigned boff = (unsigned)safe * 16u;    // byte offset into row
        asm volatile("global_load_dwordx4 %0, %1, %2"
                     : "=v"(v[k]) : "v"(boff), "s"(rowp));
    }
    asm volatile("s_waitcnt vmcnt(0)" ::: "memory");
    __builtin_amdgcn_sched_barrier(0);
#pragma unroll
    for (int k = 0; k < NCHUNK; ++k)                   // mask tail duplicates
        if (tid + (k << 9) >= NV4)
            v[k] = (f32x4){-INFINITY, -INFINITY, -INFINITY, -INFINITY};

    // ---- Phase 2: row max — one LDS round trip per wave ----
    float tm = -INFINITY;
#pragma unroll
    for (int k = 0; k < NCHUNK; ++k)
        tm = fmaxf(tm, fmaxf(fmaxf(v[k][0], v[k][1]), fmaxf(v[k][2], v[k][3])));
    const float wm  = wave_max(tm);              // raw-x wave max
    const float wmX = wm * am1;                  // X-domain
    if (lane == 0) atomicMax(&s_gmax, fflip(wmX));
    const unsigned r = __hip_atomic_load(&s_gmax, __ATOMIC_RELAXED,
                                         __HIP_MEMORY_SCOPE_WORKGROUP);
    // run <= true gmax always; staleness only adds harmless candidates.
    const float run   = fmaxf(funflip(r), wmX);
    const float thr_x = (run - 1.0f) * inv_am1;  // threshold in raw-x domain

    // ---- Phase 3: candidate append (solve input only), wave-aggregated ----
    int cnt = 0;
#pragma unroll
    for (int k = 0; k < NCHUNK; ++k) {
        cnt += (v[k][0] > thr_x) + (v[k][1] > thr_x)
             + (v[k][2] > thr_x) + (v[k][3] > thr_x);
    }
    // inclusive shfl scan over 64 lanes
    int inc = cnt;
#pragma unroll
    for (int off = 1; off < 64; off <<= 1) {
        const int t = __shfl_up(inc, off, 64);
        if (lane >= off) inc += t;
    }
    const int total = __shfl(inc, 63, 64);
    if (total > 0) {
        int base = 0;
        if (lane == 63) base = atomicAdd(&s_cnt, total);
        base = __shfl(base, 63, 64);
        int pos = base + (inc - cnt);            // exclusive offset
        auto append1 = [&](float val) {
            if (val > thr_x) {
                if (pos < CAP) s_val[pos] = val * am1;
                ++pos;
            }
        };
#pragma unroll
        for (int k = 0; k < NCHUNK; ++k) {
            append1(v[k][0]); append1(v[k][1]);
            append1(v[k][2]); append1(v[k][3]);
        }
    }
    __syncthreads();
    const int   n_act   = s_cnt;
    const float max_val = funflip(s_gmax);       // exact global max (X-domain)
    const float tau_lo0 = max_val - 1.0f;

    if (n_act <= CAP) {
        // ---- Solve on wave 0 (extras in candidate list contribute exactly 0)
        if (wid == 0) {
            float tau, S;
            if (sq) {
                tau = tau_lo0;                   // monotone Newton
                for (int it = 0; it < NEWTON_MAX; ++it) {
                    float s1 = 0.f, s2 = 0.f;
                    for (int i = lane; i < n_act; i += 64) {
                        const float z = fmaxf(s_val[i] - tau, 0.f);
                        s1 += z; s2 += z * z;
                    }
#pragma unroll
                    for (int off = 32; off > 0; off >>= 1) {
                        s1 += __shfl_xor(s1, off, 64);
                        s2 += __shfl_xor(s2, off, 64);
                    }
                    const float dtau = (s2 - 1.0f) / fmaxf(2.0f * s1, 1e-30f);
                    tau += dtau;
                    if (dtau < 1e-7f * fmaxf(1.0f, fabsf(tau))) break;
                }
                float s2 = 0.f;
                for (int i = lane; i < n_act; i += 64) {
                    const float z = fmaxf(s_val[i] - tau, 0.f);
                    s2 += z * z;
                }
                S = wave_sum(s2);
            } else {
                // generic alpha: faithful 50-step bisection over candidates
                const float tau_hi = max_val - powf(1.0f / (float)D_DIM, am1);
                float dm = tau_hi - tau_lo0;
                float s = 0.f;
                for (int i = lane; i < n_act; i += 64)
                    s += pf(s_val[i] - tau_lo0, sq, expo);
                s = wave_sum(s);
                const float f_lo = s - 1.0f;
                float tlo = tau_lo0, tau_m = tau_lo0, fsum = s;
                for (int it = 0; it < NITER; ++it) {
                    dm *= 0.5f;
                    tau_m = tlo + dm;
                    float t = 0.f;
                    for (int i = lane; i < n_act; i += 64)
                        t += pf(s_val[i] - tau_m, sq, expo);
                    t = wave_sum(t);
                    fsum = t;
                    if ((t - 1.0f) * f_lo >= 0.0f) tlo = tau_m;
                }
                tau = tau_m; S = fsum;
            }
            if (lane == 0) { s_bc[0] = tau; s_bc[1] = S; }
        }
        __syncthreads();   // publish tau, S

        // ---- Phase 4: single coalesced write pass from registers ----
        // Non-candidates compute z=0 -> p=0 exactly (== scatter-onto-zeros).
        const float tau_f = s_bc[0];
        const float invS  = 1.0f / s_bc[1];
#pragma unroll
        for (int k = 0; k < NCHUNK; ++k) {
            const int i4 = tid + (k << 9);
            if (i4 < NV4) {
                float4 o;
                {
                    const float z = fmaxf(v[k][0] * am1 - tau_f, 0.f);
                    o.x = (sq ? z * z : powf(z, expo)) * invS;
                }
                {
                    const float z = fmaxf(v[k][1] * am1 - tau_f, 0.f);
                    o.y = (sq ? z * z : powf(z, expo)) * invS;
                }
                {
                    const float z = fmaxf(v[k][2] * am1 - tau_f, 0.f);
                    o.z = (sq ? z * z : powf(z, expo)) * invS;
                }
                {
                    const float z = fmaxf(v[k][3] * am1 - tau_f, 0.f);
                    o.w = (sq ? z * z : powf(z, expo)) * invS;
                }
                o4[i4] = o;
            }
        }
    } else {
        // ---- Overflow fallback (pathological inputs only): full-row
        //      50-step bisection re-reading x from global each iteration.
        const float tau_hi = max_val - powf(1.0f / (float)D_DIM, am1);
        float dm = tau_hi - tau_lo0;
        float s = 0.f;
        for (int i4 = tid; i4 < NV4; i4 += BLOCK) {
            float4 vv = x4[i4];
            s += pf(vv.x * am1 - tau_lo0, sq, expo) + pf(vv.y * am1 - tau_lo0, sq, expo)
               + pf(vv.z * am1 - tau_lo0, sq, expo) + pf(vv.w * am1 - tau_lo0, sq, expo);
        }
        s = wave_sum(s);
        __syncthreads();
        if (lane == 0) s_red[wid] = s;
        __syncthreads();
        float tot = 0.f;
#pragma unroll
        for (int w = 0; w < NWAVE; ++w) tot += s_red[w];
        const float f_lo = tot - 1.0f;
        float tlo = tau_lo0, tau_m = tau_lo0, fsum = tot;
        for (int it = 0; it < NITER; ++it) {
            dm *= 0.5f;
            tau_m = tlo + dm;
            float t = 0.f;
            for (int i4 = tid; i4 < NV4; i4 += BLOCK) {
                float4 vv = x4[i4];
                t += pf(vv.x * am1 - tau_m, sq, expo) + pf(vv.y * am1 - tau_m, sq, expo)
                   + pf(vv.z * am1 - tau_m, sq, expo) + pf(vv.w * am1 - tau_m, sq, expo);
            }
            t = wave_sum(t);
            __syncthreads();
            if (lane == 0) s_red[wid] = t;
            __syncthreads();
            float tt = 0.f;
#pragma unroll
            for (int w = 0; w < NWAVE; ++w) tt += s_red[w];
            fsum = tt;
            if ((tt - 1.0f) * f_lo >= 0.0f) tlo = tau_m;
        }
        const float invS = 1.0f / fsum;
        for (int i4 = tid; i4 < NV4; i4 += BLOCK) {
            float4 vv = x4[i4];
            float4 o;
            o.x = pf(vv.x * am1 - tau_m, sq, expo) * invS;
            o.y = pf(vv.y * am1 - tau_m, sq, expo) * invS;
            o.z = pf(vv.z * am1 - tau_m, sq, expo) * invS;
            o.w = pf(vv.w * am1 - tau_m, sq, expo) * invS;
            o4[i4] = o;
        }
    }
}

extern "C" void kernel_launch(void* const* d_in, const int* in_sizes, int n_in,
                              void* d_out, int out_size, void* d_ws, size_t ws_size,
                              hipStream_t stream) {
    const float* x       = (const float*)d_in[0];
    const float* alpha_p = (const float*)d_in[1];
    float* out           = (float*)d_out;
    const int rows       = in_sizes[0] / D_DIM;   // 2048
    entmax_bisect_kernel<<<rows, BLOCK, 0, stream>>>(x, alpha_p, out);
}